// Round 4
// baseline (84.695 us; speedup 1.0000x reference)
//
#include <hip/hip_runtime.h>
#include <math.h>

// Problem constants (fixed by reference: inp (4,16,32,32) f32, weight (64,144) f32)
constexpr int F_IN   = 144;   // 16 ch * 9 taps
constexpr int F_OUT  = 64;
constexpr int H_IMG  = 32;
constexpr int W_IMG  = 32;
constexpr int NPIX   = 4 * H_IMG * W_IMG;  // 4096
constexpr int PPB    = 4;                  // pixels per block
constexpr int WPP    = 2;                  // waves per pixel
constexpr int NTHR   = PPB * WPP * 64;     // 512
#define MAX_SPIKE 100.0f

// ---------------------------------------------------------------------------
// Quant kernel: byte-identical math to validated rounds (absmax 0.00390625).
// ---------------------------------------------------------------------------
__global__ __launch_bounds__(256) void quant_kernel(
    const float* __restrict__ w,
    float* __restrict__ wqT)   // (144,64) transposed
{
#pragma clang fp contract(off)
    __shared__ float wred[4];
    const int tid = threadIdx.x;

    float m = 0.f;
    {
        const float4* w4 = (const float4*)w;
        for (int i = tid; i < (F_OUT * F_IN) / 4; i += 256) {
            const float4 v = w4[i];
            m = fmaxf(m, fmaxf(fmaxf(fabsf(v.x), fabsf(v.y)),
                               fmaxf(fabsf(v.z), fabsf(v.w))));
        }
    }
    for (int s = 32; s > 0; s >>= 1)
        m = fmaxf(m, __shfl_xor(m, s, 64));
    if ((tid & 63) == 0) wred[tid >> 6] = m;
    __syncthreads();
    const float mw = fmaxf(fmaxf(wred[0], wred[1]), fmaxf(wred[2], wred[3]));
    const float alpha = tanhf(mw);

    const int i = blockIdx.x * 256 + tid;   // 36*256 = 9216 exactly
    const int o = i / F_IN;
    const int f = i - o * F_IN;
    const float t = tanhf(w[i]);
    float x = t / alpha;                       // f32 divide (mirrors np)
    x = fminf(fmaxf(x, -1.f), 1.f) * 127.f;    // clip then *qmax
    const float r = rintf(x);                  // round half-to-even
    wqT[f * F_OUT + o] = r * alpha / 127.f;    // mul then div (mirrors np)
}

// ---------------------------------------------------------------------------
// Spike scan v7: 2 WAVES PER PIXEL (occupancy attack).
// Round-2/3 counters: whole grid resident at only 4 waves/SIMD, VALUBusy 45%
// -> each wave is ~89% stalled. This version doubles resident waves to
// 8/SIMD (8192 waves = 32/CU, the hardware max) and cuts per-wave sort work
// from 432 to 288 key-compares:
//   wave half h of a pixel owns features f0 = h*64+lane (0..127) and the
//   leftover f1 = 128+h*8+lane for lane<8 (128..143).
// Phases: [keys -> sync -> ranks -> scatter -> sync -> scan(half 0 only)].
// Record-hi repack phase removed: scan reads sorted values directly via
// float4 broadcast reads (identical float values -> bit-exact).
// wq read from global (36KB, L2-resident, wave-broadcast 256B/step).
// ---------------------------------------------------------------------------
__global__ __launch_bounds__(NTHR, 8) void spike_scan_kernel(
    const float* __restrict__ inp,   // (4,16,32,32)
    const float* __restrict__ wq,    // (144,64) quantized transposed
    float* __restrict__ out)         // (4,64,32,32)
{
#pragma clang fp contract(off)
    __shared__ __align__(16) unsigned long long kr[PPB][F_IN]; // 4608 B keys
    __shared__ __align__(16) float svv[PPB][152];              // 2432 B sorted vals (+sentinel@144)
    __shared__ __align__(16) unsigned sof[PPB][F_IN];          // 2304 B sorted wq offsets

    const int tid  = threadIdx.x;
    const int lane = tid & 63;
    const int wave = tid >> 6;
    const int pix  = wave >> 1;                  // pixel-in-block 0..3
    const int half = wave & 1;
    const int p    = blockIdx.x * PPB + pix;     // pixel id
    const int b    = p >> 10;
    const int l    = p & 1023;
    const int h    = l >> 5;
    const int wcol = l & 31;

    // ---- phase 1: load owned features, build + publish keys ----
    const int f0 = half * 64 + lane;             // 0..127
    const int f1 = 128 + half * 8 + lane;        // 128..143 valid for lane<8
    const bool has1 = (lane < 8);
    float v0, v1 = MAX_SPIKE;
    {
        const int c  = f0 / 9;
        const int r  = f0 - c * 9;
        const int kh = r / 3;
        const int kw = r - kh * 3;
        const int hh = h + kh - 1;
        const int ww = wcol + kw - 1;
        float x = 0.f;
        if (hh >= 0 && hh < H_IMG && ww >= 0 && ww < W_IMG)
            x = inp[((b * 16 + c) * H_IMG + hh) * W_IMG + ww];
        v0 = (x < 0.1f) ? MAX_SPIKE : x;
        kr[pix][f0] = ((unsigned long long)__float_as_uint(v0) << 8) | (unsigned)f0;
    }
    if (has1) {
        const int c  = f1 / 9;
        const int r  = f1 - c * 9;
        const int kh = r / 3;
        const int kw = r - kh * 3;
        const int hh = h + kh - 1;
        const int ww = wcol + kw - 1;
        float x = 0.f;
        if (hh >= 0 && hh < H_IMG && ww >= 0 && ww < W_IMG)
            x = inp[((b * 16 + c) * H_IMG + hh) * W_IMG + ww];
        v1 = (x < 0.1f) ? MAX_SPIKE : x;
        kr[pix][f1] = ((unsigned long long)__float_as_uint(v1) << 8) | (unsigned)f1;
    }
    const unsigned long long key0 =
        ((unsigned long long)__float_as_uint(v0) << 8) | (unsigned)f0;
    const unsigned long long key1 =
        ((unsigned long long)__float_as_uint(v1) << 8) | (unsigned)f1;
    if (half == 0 && lane == 0) svv[pix][F_IN] = 1.0f;   // causality sentinel

    __syncthreads();   // keys (cross-wave) visible

    // ---- phase 2: ranks (keys unique -> strict < == exact stable perm) ----
    int r0 = 0, r1 = 0;
    {
        const ulonglong2* ks2 = (const ulonglong2*)&kr[pix][0];
#pragma unroll 4
        for (int j = 0; j < F_IN / 2; ++j) {
            const ulonglong2 kk = ks2[j];   // wave-broadcast read: conflict-free
            r0 += (kk.x < key0) + (kk.y < key0);
            r1 += (kk.x < key1) + (kk.y < key1);  // garbage for lane>=8, unused
        }
    }

    // ---- phase 3: scatter sorted values + wq row word offsets ----
    svv[pix][r0] = v0;  sof[pix][r0] = (unsigned)f0 << 6;
    if (has1) { svv[pix][r1] = v1;  sof[pix][r1] = (unsigned)f1 << 6; }

    __syncthreads();   // sorted arrays (cross-wave) visible

    // ---- phase 4: scan, half 0 only (half 1 waves retire, freeing SIMDs) ----
    if (half != 0) return;

    float s   = svv[pix][0];
    float ws  = 0.f;
    float iws = 0.f;
    float mn  = MAX_SPIKE;      // masked / never-valid lanes => exactly 100
    bool  done = false;
    for (int k0 = 0; k0 < F_IN; k0 += 8) {
        if (s >= MAX_SPIKE) break;            // sorted: rest contribute 100
        const float4 sa = *(const float4*)&svv[pix][k0];
        const float4 sb = *(const float4*)&svv[pix][k0 + 4];
        const float nxt8 = svv[pix][k0 + 8];  // k0=136 -> sentinel [144]=1.0
        const uint4  oa = *(const uint4*)&sof[pix][k0];
        const uint4  ob = *(const uint4*)&sof[pix][k0 + 4];
        const float    sv8[8] = { sa.x, sa.y, sa.z, sa.w, sb.x, sb.y, sb.z, sb.w };
        const unsigned o8[8]  = { oa.x, oa.y, oa.z, oa.w, ob.x, ob.y, ob.z, ob.w };
        float su[8], nx[8], wsu[8], iwsu[8];
#pragma unroll
        for (int u = 0; u < 8; ++u) {
            su[u] = sv8[u];
            nx[u] = (u < 7) ? sv8[u + 1] : nxt8;
            const float wvv = wq[o8[u] + lane];  // global, wave-broadcast row
            ws += wvv;
            const float prod = su[u] * wvv;   // separate rounding (no FMA)
            iws += prod;
            wsu[u]  = ws;
            iwsu[u] = iws;
        }
        // wq >= 0 => ws monotone: if last ws of batch < 1 for all lanes, the
        // whole batch is masked (contributes exactly 100) -> skip div/compares.
        if (!__all(wsu[7] < 1.0f)) {
#pragma unroll
            for (int u = 0; u < 8; ++u) {
                const float d = fmaxf(wsu[u] - 1.0f, 1e-10f); // upper clamp never binds
                const float q = iwsu[u] / d;                  // IEEE f32 divide
                const bool valid = (wsu[u] >= 1.0f) & (q >= su[u]) & (q <= nx[u]);
                if (valid & !done) { mn = q; done = true; }
            }
            if (__all(done)) break;           // windows increase: first = min
        }
        s = nxt8;
    }
    out[(b * F_OUT + lane) * 1024 + l] = mn;
}

extern "C" void kernel_launch(void* const* d_in, const int* in_sizes, int n_in,
                              void* d_out, int out_size, void* d_ws, size_t ws_size,
                              hipStream_t stream) {
    const float* inp = (const float*)d_in[0];   // 65536 elems
    const float* w   = (const float*)d_in[1];   // 9216 elems
    float* out = (float*)d_out;                 // 262144 elems
    float* wqT = (float*)d_ws;                  // 9216 floats scratch

    quant_kernel<<<36, 256, 0, stream>>>(w, wqT);
    spike_scan_kernel<<<NPIX / PPB, NTHR, 0, stream>>>(inp, wqT, out);
}